// Round 11
// baseline (202.404 us; speedup 1.0000x reference)
//
#include <hip/hip_runtime.h>
#include <math.h>

#define BB 32
#define KK 64
#define HH 96
#define WW 128
#define HW (HH*WW)             // 12288 pixels per channel plane (48 KB)
#define MAP_SIZE (BB*KK*HW)    // 25165824
#define NBK (BB*KK)            // 2048
#define GD 8                   // k-groups for the partial denominator
#define SEC 6                  // sections per plane in kernel A (2048 px each)

typedef float f32x4 __attribute__((ext_vector_type(4)));

// ---------------- Kernel A: LINEAR-read partial denominators -----------------------
// den_part[b][g][p] = sum_{k in [8g,8g+8)} exp(x[b,k,p]).  Block = (b,g,section):
// reads 8 channel planes' 8-KB sections SEQUENTIALLY (1 KB per wave instruction,
// marching contiguous 8-KB runs) — the first fully-linear read walk of the session.
// Accumulators live in 8 VGPRs; k-order within a group is serial (0..7).
__global__ __launch_bounds__(256) void den_part_k(const float* __restrict__ x,
                                                  float* __restrict__ dpart) {
    int blk = blockIdx.x;              // 32*8*6 = 1536 blocks = 6.0 per CU
    int sec = blk % SEC;
    int bg  = blk / SEC;
    int g   = bg & (GD - 1);
    int b   = bg >> 3;
    int t   = threadIdx.x;

    size_t pbase = (size_t)sec * 2048 + (size_t)t * 4;   // pixel base in plane
    f32x4 a0 = (f32x4){0.f, 0.f, 0.f, 0.f};
    f32x4 a1 = (f32x4){0.f, 0.f, 0.f, 0.f};
    #pragma unroll
    for (int k = 0; k < 8; ++k) {
        const f32x4* xp = reinterpret_cast<const f32x4*>(
            x + (size_t)(b * KK + g * 8 + k) * HW + pbase);
        f32x4 v0 = xp[0];              // px [pbase, pbase+4)
        f32x4 v1 = xp[256];            // px [pbase+1024, ...)
        a0.x += __expf(v0.x); a0.y += __expf(v0.y);
        a0.z += __expf(v0.z); a0.w += __expf(v0.w);
        a1.x += __expf(v1.x); a1.y += __expf(v1.y);
        a1.z += __expf(v1.z); a1.w += __expf(v1.w);
    }
    f32x4* dp = reinterpret_cast<f32x4*>(
        dpart + (size_t)(b * GD + g) * HW + pbase);
    dp[0]   = a0;
    dp[256] = a1;
}

// ---------------- Kernel C: combine partials -> 1/den ------------------------------
// inv[b][p] = 1 / sum_{g=0..7} den_part[b][g][p].  14 MB of cache-hot traffic.
__global__ __launch_bounds__(256) void inv_k(const float* __restrict__ dpart,
                                             float* __restrict__ invd) {
    int P = blockIdx.x * 256 + threadIdx.x;   // grid 1536*256 = 393216 exact
    int b = P / HW;
    int p = P - b * HW;
    float den = 0.f;
    #pragma unroll
    for (int g = 0; g < GD; ++g)              // serial g-order
        den += dpart[(size_t)(b * GD + g) * HW + p];
    invd[P] = 1.f / den;
}

// ---------------- Kernel B: LINEAR map write + per-(b,k) moments -------------------
// Block = one (b,k) channel plane: read x sequentially (LLC-hot after A), compute
// exp(x)*inv (inv is a 1.6-MB hot array), NT-store the map SEQUENTIALLY, and reduce
// this plane's z/sx/sy in-wave (r6/r7-verified fp32 partial scheme) -> one direct
// fp64 store per block. No atomics, no workspace memset.
__global__ __launch_bounds__(256, 2) void map_k(const float* __restrict__ x,
                                                const float* __restrict__ invd,
                                                float* __restrict__ out,
                                                double* __restrict__ sxyz) {
    int blk = blockIdx.x;              // 2048 blocks = (b,k), 8 per CU
    int k   = blk & (KK - 1);
    int b   = blk >> 6;
    int t   = threadIdx.x;

    const f32x4* xp = reinterpret_cast<const f32x4*>(x   + (size_t)blk * HW);
    f32x4*       op = reinterpret_cast<f32x4*>      (out + (size_t)blk * HW);
    const f32x4* ip = reinterpret_cast<const f32x4*>(invd + (size_t)b * HW);

    float z = 0.f, w = 0.f, syw = 0.f;
    #pragma unroll
    for (int i = 0; i < 12; ++i) {
        int idx = i * 256 + t;
        f32x4 v  = xp[idx];
        f32x4 iv = ip[idx];
        f32x4 m;
        m.x = __expf(v.x) * iv.x;
        m.y = __expf(v.y) * iv.y;
        m.z = __expf(v.z) * iv.z;
        m.w = __expf(v.w) * iv.w;
        __builtin_nontemporal_store(m, op + idx);
        float s = (m.x + m.y) + (m.z + m.w);
        z   += s;
        w   += fmaf(3.f, m.w, fmaf(2.f, m.z, m.y));
        syw  = fmaf(s, (float)(8 * i), syw);        // gy = 8i + (t>>5)
    }
    // px p = i*1024 + 4t + c:  gx = (4t)&127 + c (no row wrap),  gy = 8i + (t>>5)
    float gxb = (float)((t * 4) & (WW - 1));
    float gyc = (float)(t >> 5);
    double dz = (double)z;
    double dx = (double)fmaf(gxb, z, w);
    double dy = (double)fmaf(gyc, z, syw);

    #pragma unroll
    for (int off = 1; off < 64; off <<= 1) {
        dz += __shfl_xor(dz, off, 64);
        dx += __shfl_xor(dx, off, 64);
        dy += __shfl_xor(dy, off, 64);
    }
    __shared__ double wz[4], wx[4], wy[4];
    int lane = t & 63, wid = t >> 6;
    if (lane == 0) { wz[wid] = dz; wx[wid] = dx; wy[wid] = dy; }
    __syncthreads();
    if (t == 0) {
        double Z  = ((wz[0] + wz[1]) + wz[2]) + wz[3];
        double SX = ((wx[0] + wx[1]) + wx[2]) + wx[3];
        double SY = ((wy[0] + wy[1]) + wy[2]) + wy[3];
        sxyz[blk * 3 + 0] = SX;
        sxyz[blk * 3 + 1] = SY;
        sxyz[blk * 3 + 2] = Z;
    }
}

// ---------------- Keypoints: inclusive fp64 scan over flattened (b,k) ----------------
__global__ __launch_bounds__(256) void keypoint_k(const double* __restrict__ sxyz,
                                                  float* __restrict__ kp,
                                                  float* __restrict__ zeta) {
    const int PT = NBK / 256;   // 8
    int t = threadIdx.x;
    int lane = t & 63, wid = t >> 6;

    double vx[PT], vy[PT], vz[PT];
    double cx = 0.0, cy = 0.0;
    #pragma unroll
    for (int e = 0; e < PT; ++e) {
        int idx = t * PT + e;
        cx += sxyz[idx * 3 + 0]; vx[e] = cx;
        cy += sxyz[idx * 3 + 1]; vy[e] = cy;
        vz[e] = sxyz[idx * 3 + 2];
    }
    double tx = cx, ty = cy;
    for (int off = 1; off < 64; off <<= 1) {
        double ax = __shfl_up(tx, off, 64);
        double ay = __shfl_up(ty, off, 64);
        if (lane >= off) { tx += ax; ty += ay; }
    }
    __shared__ double wxs[4], wys[4];
    if (lane == 63) { wxs[wid] = tx; wys[wid] = ty; }
    __syncthreads();
    double offx = tx - cx, offy = ty - cy;
    for (int w2 = 0; w2 < wid; ++w2) { offx += wxs[w2]; offy += wys[w2]; }

    #pragma unroll
    for (int e = 0; e < PT; ++e) {
        int idx = t * PT + e;
        double zz = vz[e];
        double kx = rint((vx[e] + offx) / zz);
        double ky = rint((vy[e] + offy) / zz);
        float fkx = (float)kx, fky = (float)ky;
        if (fkx > 128.0f || fkx < 0.0f) fkx = 64.0f;   // PRE_WIDTH clamp -> center
        if (fky > 96.0f  || fky < 0.0f) fky = 48.0f;   // PRE_HEIGHT clamp -> center
        kp[idx * 2 + 0] = fkx;
        kp[idx * 2 + 1] = fky;
        zeta[idx] = (float)zz;
    }
}

extern "C" void kernel_launch(void* const* d_in, const int* in_sizes, int n_in,
                              void* d_out, int out_size, void* d_ws, size_t ws_size,
                              hipStream_t stream) {
    const float* x = (const float*)d_in[0];
    float* out  = (float*)d_out;
    float* map  = out;                         // [B,K,H,W]
    float* kp   = out + MAP_SIZE;              // [B,K,2]
    float* zeta = out + MAP_SIZE + NBK * 2;    // [B,K]
    double* sxyz = (double*)d_ws;              // [NBK][3] fp64 moments (48 KB)
    float*  invd = (float*)((char*)d_ws + 65536);   // [B*HW] 1/den, 1.57 MB
    // den_part scratch lives INSIDE the map region: A writes it, C reads it,
    // B fully overwrites the map afterwards (stream-ordered, no aliasing hazard).
    float* dpart = map;                        // [B][GD][HW] = 12.6 MB

    den_part_k<<< BB * GD * SEC, 256, 0, stream >>> (x, dpart);
    inv_k     <<< (BB * HW) / 256, 256, 0, stream >>> (dpart, invd);
    map_k     <<< NBK, 256, 0, stream >>> (x, invd, map, sxyz);
    keypoint_k<<< 1,   256, 0, stream >>> (sxyz, kp, zeta);
}